// Round 5
// baseline (76.161 us; speedup 1.0000x reference)
//
#include <hip/hip_runtime.h>

#define NB 128      // batch
#define NC 22       // classes
#define NP 1024     // points per class
#define SPLIT 2     // p-split: blocks per batch
#define TPB 512     // 8 waves; wave w sweeps q-eighth w
#define PPB (NP / SPLIT)   // output points per block = 512
#define PPT 8              // output points per lane (sym path): 64*8 = 512 = PPB
#define NW  (TPB / 64)     // waves per block = 8
#define QW  (NP / NW)      // q's per wave = 128
#define MARGIN_F 0.01f

__global__ void adl_zero_kernel(float* out) { out[0] = 0.0f; }

__global__ __launch_bounds__(TPB) void adl_kernel(
    const float* __restrict__ poses_pred,   // [B,C,4]
    const float* __restrict__ poses_target, // [B,C,4]
    const int*   __restrict__ labels,       // [B]
    const float* __restrict__ points,       // [C,P,3]
    const int*   __restrict__ symmetry,     // [C]
    float* __restrict__ out)
{
    const int b     = blockIdx.x >> 1;      // SPLIT == 2
    const int part  = blockIdx.x & 1;
    const int label = labels[b];
    if (label <= 0) return;  // background contributes 0 (uniform block exit)

    // ---- quaternions -> rotation matrices (uniform per block) ----
    const float* q1 = poses_pred   + (size_t)(b * NC + label) * 4;
    const float* q2 = poses_target + (size_t)(b * NC + label) * 4;
    float s = q1[0], u = q1[1], v = q1[2], w = q1[3];
    float R1[9];
    R1[0] = 1.f - 2.f * (v * v + w * w); R1[1] = 2.f * (u * v - s * w); R1[2] = 2.f * (u * w + s * v);
    R1[3] = 2.f * (u * v + s * w); R1[4] = 1.f - 2.f * (u * u + w * w); R1[5] = 2.f * (v * w - s * u);
    R1[6] = 2.f * (u * w - s * v); R1[7] = 2.f * (v * w + s * u); R1[8] = 1.f - 2.f * (u * u + v * v);
    s = q2[0]; u = q2[1]; v = q2[2]; w = q2[3];
    float R2[9];
    R2[0] = 1.f - 2.f * (v * v + w * w); R2[1] = 2.f * (u * v - s * w); R2[2] = 2.f * (u * w + s * v);
    R2[3] = 2.f * (u * v + s * w); R2[4] = 1.f - 2.f * (u * u + w * w); R2[5] = 2.f * (v * w - s * u);
    R2[6] = 2.f * (u * w - s * v); R2[7] = 2.f * (v * w + s * u); R2[8] = 1.f - 2.f * (u * u + v * v);

    const float* pt = points + (size_t)label * NP * 3;
    const bool is_sym = symmetry[label] > 0;
    float acc = 0.0f;

    if (is_sym) {
        // ---- stage ALL target-pose points as (-2bx,-2by,-2bz, ||b||^2) ----
        __shared__ float4 x2s[NP];         // 16 KB
        __shared__ float  msh[NW * PPB];   // per-wave partial mins per p-slot, 16 KB
        for (int q = threadIdx.x; q < NP; q += TPB) {
            float qx = pt[q * 3 + 0], qy = pt[q * 3 + 1], qz = pt[q * 3 + 2];
            float bx = R2[0] * qx + R2[1] * qy + R2[2] * qz;
            float by = R2[3] * qx + R2[4] * qy + R2[5] * qz;
            float bz = R2[6] * qx + R2[7] * qy + R2[8] * qz;
            x2s[q] = make_float4(-2.f * bx, -2.f * by, -2.f * bz,
                                 bx * bx + by * by + bz * bz);
        }

        // this lane's PPT=8 output points, rotated by R1 (registers)
        const int lane = threadIdx.x & 63;
        const int wv   = threadIdx.x >> 6;        // q-eighth index, 0..7
        float ax[PPT], ay[PPT], az[PPT], m[PPT];
#pragma unroll
        for (int i = 0; i < PPT; ++i) {
            int p = part * PPB + lane + i * 64;
            float px = pt[p * 3 + 0], py = pt[p * 3 + 1], pz = pt[p * 3 + 2];
            ax[i] = R1[0] * px + R1[1] * py + R1[2] * pz;
            ay[i] = R1[3] * px + R1[4] * py + R1[5] * pz;
            az[i] = R1[6] * px + R1[7] * py + R1[8] * pz;
            m[i]  = 3.0e38f;
        }
        __syncthreads();

        // ADD-S sweep: this wave covers q in [wv*QW, wv*QW + QW)
        const int q0 = wv * QW;
#pragma unroll 1
        for (int q = 0; q < QW; q += 4) {
#pragma unroll
            for (int j = 0; j < 4; ++j) {
                float4 t = x2s[q0 + q + j];   // wave-uniform -> LDS broadcast
#pragma unroll
                for (int i = 0; i < PPT; ++i) {
                    m[i] = fminf(m[i],
                                 fmaf(ax[i], t.x, fmaf(ay[i], t.y, fmaf(az[i], t.z, t.w))));
                }
            }
        }
        // fold n1 in (constant per p over the q-min), publish per-wave partials
#pragma unroll
        for (int i = 0; i < PPT; ++i) {
            float n1 = ax[i] * ax[i] + ay[i] * ay[i] + az[i] * az[i];
            msh[wv * PPB + lane + i * 64] = n1 + m[i];
        }
        __syncthreads();

        // cross-wave min: thread t owns p-slot t (PPB == TPB)
        const int sl = threadIdx.x;
        float mm = 3.0e38f;
#pragma unroll
        for (int wvi = 0; wvi < NW; ++wvi)
            mm = fminf(mm, msh[wvi * PPB + sl]);
        acc = fmaxf(0.5f * mm - MARGIN_F, 0.0f);
    } else {
        // ADD: matched-point distance; thread t owns p-slot t (no LDS, no barrier)
        const int p = part * PPB + (int)threadIdx.x;
        const float px = pt[p * 3 + 0], py = pt[p * 3 + 1], pz = pt[p * 3 + 2];
        const float ax0 = R1[0] * px + R1[1] * py + R1[2] * pz;
        const float ay0 = R1[3] * px + R1[4] * py + R1[5] * pz;
        const float az0 = R1[6] * px + R1[7] * py + R1[8] * pz;
        const float bx0 = R2[0] * px + R2[1] * py + R2[2] * pz;
        const float by0 = R2[3] * px + R2[4] * py + R2[5] * pz;
        const float bz0 = R2[6] * px + R2[7] * py + R2[8] * pz;
        const float dx = ax0 - bx0, dy = ay0 - by0, dz = az0 - bz0;
        const float d = dx * dx + dy * dy + dz * dz;
        acc = fmaxf(0.5f * d - MARGIN_F, 0.0f);
    }

    // ---- block reduction: 64-lane shuffle, then 8 waves via LDS ----
#pragma unroll
    for (int off = 32; off > 0; off >>= 1)
        acc += __shfl_down(acc, off);
    __shared__ float wsum[NW];
    const int lane = threadIdx.x & 63, wid = threadIdx.x >> 6;
    if (lane == 0) wsum[wid] = acc;
    __syncthreads();
    if (threadIdx.x == 0) {
        float ssum = 0.f;
#pragma unroll
        for (int i = 0; i < NW; ++i) ssum += wsum[i];
        atomicAdd(out, ssum * (1.0f / (float)(NB * NP)));
    }
}

extern "C" void kernel_launch(void* const* d_in, const int* in_sizes, int n_in,
                              void* d_out, int out_size, void* d_ws, size_t ws_size,
                              hipStream_t stream) {
    const float* poses_pred   = (const float*)d_in[0];
    const float* poses_target = (const float*)d_in[1];
    const int*   poses_labels = (const int*)d_in[2];
    const float* points       = (const float*)d_in[3];
    const int*   symmetry     = (const int*)d_in[4];
    float* out = (float*)d_out;

    adl_zero_kernel<<<1, 1, 0, stream>>>(out);
    adl_kernel<<<NB * SPLIT, TPB, 0, stream>>>(poses_pred, poses_target,
                                               poses_labels, points, symmetry, out);
}

// Round 7
// 74.875 us; speedup vs baseline: 1.0172x; 1.0172x over previous
//
#include <hip/hip_runtime.h>

#define NB 128      // batch
#define NC 22       // classes
#define NP 1024     // points per class
#define SPLIT 2     // p-split: blocks per batch
#define NBLK (NB * SPLIT)  // 256 partial-sum slots
#define TPB 512     // 8 waves; wave w sweeps q-eighth w
#define PPB (NP / SPLIT)   // output points per block = 512
#define PPT 8              // output points per lane (sym path): 64*8 = 512 = PPB
#define NW  (TPB / 64)     // waves per block = 8
#define QW  (NP / NW)      // q's per wave = 128
#define MARGIN_F 0.01f

__global__ __launch_bounds__(TPB) void adl_main_kernel(
    const float* __restrict__ poses_pred,   // [B,C,4]
    const float* __restrict__ poses_target, // [B,C,4]
    const int*   __restrict__ labels,       // [B]
    const float* __restrict__ points,       // [C,P,3]
    const int*   __restrict__ symmetry,     // [C]
    float* __restrict__ partials)           // [NBLK] in d_ws
{
    const int b     = blockIdx.x >> 1;      // SPLIT == 2
    const int part  = blockIdx.x & 1;
    const int label = labels[b];
    if (label <= 0) {                        // background: contributes 0
        if (threadIdx.x == 0) partials[blockIdx.x] = 0.0f;
        return;
    }

    // ---- quaternions -> rotation matrices (uniform per block) ----
    const float* q1 = poses_pred   + (size_t)(b * NC + label) * 4;
    const float* q2 = poses_target + (size_t)(b * NC + label) * 4;
    float s = q1[0], u = q1[1], v = q1[2], w = q1[3];
    float R1[9];
    R1[0] = 1.f - 2.f * (v * v + w * w); R1[1] = 2.f * (u * v - s * w); R1[2] = 2.f * (u * w + s * v);
    R1[3] = 2.f * (u * v + s * w); R1[4] = 1.f - 2.f * (u * u + w * w); R1[5] = 2.f * (v * w - s * u);
    R1[6] = 2.f * (u * w - s * v); R1[7] = 2.f * (v * w + s * u); R1[8] = 1.f - 2.f * (u * u + v * v);
    s = q2[0]; u = q2[1]; v = q2[2]; w = q2[3];
    float R2[9];
    R2[0] = 1.f - 2.f * (v * v + w * w); R2[1] = 2.f * (u * v - s * w); R2[2] = 2.f * (u * w + s * v);
    R2[3] = 2.f * (u * v + s * w); R2[4] = 1.f - 2.f * (u * u + w * w); R2[5] = 2.f * (v * w - s * u);
    R2[6] = 2.f * (u * w - s * v); R2[7] = 2.f * (v * w + s * u); R2[8] = 1.f - 2.f * (u * u + v * v);

    const float* pt = points + (size_t)label * NP * 3;
    const bool is_sym = symmetry[label] > 0;
    float acc = 0.0f;

    if (is_sym) {
        // ---- stage ALL target-pose points as (-2bx,-2by,-2bz, ||b||^2) ----
        __shared__ float4 x2s[NP];         // 16 KB
        __shared__ float  msh[NW * PPB];   // per-wave partial mins per p-slot, 16 KB
        for (int q = threadIdx.x; q < NP; q += TPB) {
            float qx = pt[q * 3 + 0], qy = pt[q * 3 + 1], qz = pt[q * 3 + 2];
            float bx = R2[0] * qx + R2[1] * qy + R2[2] * qz;
            float by = R2[3] * qx + R2[4] * qy + R2[5] * qz;
            float bz = R2[6] * qx + R2[7] * qy + R2[8] * qz;
            x2s[q] = make_float4(-2.f * bx, -2.f * by, -2.f * bz,
                                 bx * bx + by * by + bz * bz);
        }

        // this lane's PPT=8 output points, rotated by R1 (registers)
        const int lane = threadIdx.x & 63;
        const int wv   = threadIdx.x >> 6;        // q-eighth index, 0..7
        float ax[PPT], ay[PPT], az[PPT], m[PPT];
#pragma unroll
        for (int i = 0; i < PPT; ++i) {
            int p = part * PPB + lane + i * 64;
            float px = pt[p * 3 + 0], py = pt[p * 3 + 1], pz = pt[p * 3 + 2];
            ax[i] = R1[0] * px + R1[1] * py + R1[2] * pz;
            ay[i] = R1[3] * px + R1[4] * py + R1[5] * pz;
            az[i] = R1[6] * px + R1[7] * py + R1[8] * pz;
            m[i]  = 3.0e38f;
        }
        __syncthreads();

        // ADD-S sweep: this wave covers q in [wv*QW, wv*QW + QW)
        const int q0 = wv * QW;
#pragma unroll 1
        for (int q = 0; q < QW; q += 4) {
#pragma unroll
            for (int j = 0; j < 4; ++j) {
                float4 t = x2s[q0 + q + j];   // wave-uniform -> LDS broadcast
#pragma unroll
                for (int i = 0; i < PPT; ++i) {
                    m[i] = fminf(m[i],
                                 fmaf(ax[i], t.x, fmaf(ay[i], t.y, fmaf(az[i], t.z, t.w))));
                }
            }
        }
        // fold n1 in (constant per p over the q-min), publish per-wave partials
#pragma unroll
        for (int i = 0; i < PPT; ++i) {
            float n1 = ax[i] * ax[i] + ay[i] * ay[i] + az[i] * az[i];
            msh[wv * PPB + lane + i * 64] = n1 + m[i];
        }
        __syncthreads();

        // cross-wave min: thread t owns p-slot t (PPB == TPB)
        const int sl = threadIdx.x;
        float mm = 3.0e38f;
#pragma unroll
        for (int wvi = 0; wvi < NW; ++wvi)
            mm = fminf(mm, msh[wvi * PPB + sl]);
        acc = fmaxf(0.5f * mm - MARGIN_F, 0.0f);
    } else {
        // ADD: matched-point distance; thread t owns p-slot t (no LDS, no barrier)
        const int p = part * PPB + (int)threadIdx.x;
        const float px = pt[p * 3 + 0], py = pt[p * 3 + 1], pz = pt[p * 3 + 2];
        const float ax0 = R1[0] * px + R1[1] * py + R1[2] * pz;
        const float ay0 = R1[3] * px + R1[4] * py + R1[5] * pz;
        const float az0 = R1[6] * px + R1[7] * py + R1[8] * pz;
        const float bx0 = R2[0] * px + R2[1] * py + R2[2] * pz;
        const float by0 = R2[3] * px + R2[4] * py + R2[5] * pz;
        const float bz0 = R2[6] * px + R2[7] * py + R2[8] * pz;
        const float dx = ax0 - bx0, dy = ay0 - by0, dz = az0 - bz0;
        const float d = dx * dx + dy * dy + dz * dz;
        acc = fmaxf(0.5f * d - MARGIN_F, 0.0f);
    }

    // ---- block reduction: 64-lane shuffle, then 8 waves via LDS ----
#pragma unroll
    for (int off = 32; off > 0; off >>= 1)
        acc += __shfl_down(acc, off);
    __shared__ float wsum[NW];
    const int lane = threadIdx.x & 63, wid = threadIdx.x >> 6;
    if (lane == 0) wsum[wid] = acc;
    __syncthreads();
    if (threadIdx.x == 0) {
        float ssum = 0.f;
#pragma unroll
        for (int i = 0; i < NW; ++i) ssum += wsum[i];
        partials[blockIdx.x] = ssum;   // unique slot: plain store, no atomic
    }
}

// reduce NBLK partials -> single scalar (plain store, no zero-init needed)
__global__ __launch_bounds__(NBLK) void adl_reduce_kernel(
    const float* __restrict__ partials, float* __restrict__ out)
{
    float acc = partials[threadIdx.x] * (1.0f / (float)(NB * NP));
#pragma unroll
    for (int off = 32; off > 0; off >>= 1)
        acc += __shfl_down(acc, off);
    __shared__ float wsum[NBLK / 64];
    const int lane = threadIdx.x & 63, wid = threadIdx.x >> 6;
    if (lane == 0) wsum[wid] = acc;
    __syncthreads();
    if (threadIdx.x == 0) {
        float ssum = 0.f;
#pragma unroll
        for (int i = 0; i < NBLK / 64; ++i) ssum += wsum[i];
        out[0] = ssum;
    }
}

extern "C" void kernel_launch(void* const* d_in, const int* in_sizes, int n_in,
                              void* d_out, int out_size, void* d_ws, size_t ws_size,
                              hipStream_t stream) {
    const float* poses_pred   = (const float*)d_in[0];
    const float* poses_target = (const float*)d_in[1];
    const int*   poses_labels = (const int*)d_in[2];
    const float* points       = (const float*)d_in[3];
    const int*   symmetry     = (const int*)d_in[4];
    float* out      = (float*)d_out;
    float* partials = (float*)d_ws;

    adl_main_kernel<<<NBLK, TPB, 0, stream>>>(poses_pred, poses_target,
                                              poses_labels, points, symmetry,
                                              partials);
    adl_reduce_kernel<<<1, NBLK, 0, stream>>>(partials, out);
}

// Round 8
// 72.792 us; speedup vs baseline: 1.0463x; 1.0286x over previous
//
#include <hip/hip_runtime.h>

#define NB 128      // batch
#define NC 22       // classes
#define NP 1024     // points per class
#define SPLIT 4     // p-split: blocks per batch (finer granule -> better balance)
#define NBLK (NB * SPLIT)  // 512 partial-sum slots
#define TPB 512     // 8 waves; wave w sweeps q-eighth w
#define PPB (NP / SPLIT)   // output points per block = 256
#define PPT (PPB / 64)     // output points per lane (sym path) = 4
#define NW  (TPB / 64)     // waves per block = 8
#define QW  (NP / NW)      // q's per wave = 128
#define MARGIN_F 0.01f

__global__ __launch_bounds__(TPB) void adl_main_kernel(
    const float* __restrict__ poses_pred,   // [B,C,4]
    const float* __restrict__ poses_target, // [B,C,4]
    const int*   __restrict__ labels,       // [B]
    const float* __restrict__ points,       // [C,P,3]
    const int*   __restrict__ symmetry,     // [C]
    float* __restrict__ partials)           // [NBLK] in d_ws
{
    const int b     = blockIdx.x >> 2;      // SPLIT == 4
    const int part  = blockIdx.x & 3;
    const int label = labels[b];
    if (label <= 0) {                        // background: contributes 0
        if (threadIdx.x == 0) partials[blockIdx.x] = 0.0f;
        return;
    }

    // ---- quaternions -> rotation matrices (uniform per block) ----
    const float* q1 = poses_pred   + (size_t)(b * NC + label) * 4;
    const float* q2 = poses_target + (size_t)(b * NC + label) * 4;
    float s = q1[0], u = q1[1], v = q1[2], w = q1[3];
    float R1[9];
    R1[0] = 1.f - 2.f * (v * v + w * w); R1[1] = 2.f * (u * v - s * w); R1[2] = 2.f * (u * w + s * v);
    R1[3] = 2.f * (u * v + s * w); R1[4] = 1.f - 2.f * (u * u + w * w); R1[5] = 2.f * (v * w - s * u);
    R1[6] = 2.f * (u * w - s * v); R1[7] = 2.f * (v * w + s * u); R1[8] = 1.f - 2.f * (u * u + v * v);
    s = q2[0]; u = q2[1]; v = q2[2]; w = q2[3];
    float R2[9];
    R2[0] = 1.f - 2.f * (v * v + w * w); R2[1] = 2.f * (u * v - s * w); R2[2] = 2.f * (u * w + s * v);
    R2[3] = 2.f * (u * v + s * w); R2[4] = 1.f - 2.f * (u * u + w * w); R2[5] = 2.f * (v * w - s * u);
    R2[6] = 2.f * (u * w - s * v); R2[7] = 2.f * (v * w + s * u); R2[8] = 1.f - 2.f * (u * u + v * v);

    const float* pt = points + (size_t)label * NP * 3;
    const bool is_sym = symmetry[label] > 0;
    float acc = 0.0f;

    if (is_sym) {
        // ---- stage ALL target-pose points as (-2bx,-2by,-2bz, ||b||^2) ----
        // float4-vectorized: 3 float4 = 4 points per thread (threads 0..255)
        __shared__ float4 x2s[NP];         // 16 KB
        __shared__ float  msh[NW * PPB];   // per-wave partial mins per p-slot, 8 KB
        if (threadIdx.x < NP / 4) {
            const float4* pv = reinterpret_cast<const float4*>(pt);
            float4 fa = pv[3 * threadIdx.x + 0];
            float4 fb = pv[3 * threadIdx.x + 1];
            float4 fc = pv[3 * threadIdx.x + 2];
            float qx[4] = { fa.x, fa.w, fb.z, fc.y };
            float qy[4] = { fa.y, fb.x, fb.w, fc.z };
            float qz[4] = { fa.z, fb.y, fc.x, fc.w };
#pragma unroll
            for (int k = 0; k < 4; ++k) {
                float bx = R2[0] * qx[k] + R2[1] * qy[k] + R2[2] * qz[k];
                float by = R2[3] * qx[k] + R2[4] * qy[k] + R2[5] * qz[k];
                float bz = R2[6] * qx[k] + R2[7] * qy[k] + R2[8] * qz[k];
                x2s[4 * threadIdx.x + k] = make_float4(-2.f * bx, -2.f * by, -2.f * bz,
                                                       bx * bx + by * by + bz * bz);
            }
        }

        // this lane's PPT=4 output points, rotated by R1 (registers)
        const int lane = threadIdx.x & 63;
        const int wv   = threadIdx.x >> 6;        // q-eighth index, 0..7
        float ax[PPT], ay[PPT], az[PPT], m[PPT];
#pragma unroll
        for (int i = 0; i < PPT; ++i) {
            int p = part * PPB + lane + i * 64;
            float px = pt[p * 3 + 0], py = pt[p * 3 + 1], pz = pt[p * 3 + 2];
            ax[i] = R1[0] * px + R1[1] * py + R1[2] * pz;
            ay[i] = R1[3] * px + R1[4] * py + R1[5] * pz;
            az[i] = R1[6] * px + R1[7] * py + R1[8] * pz;
            m[i]  = 3.0e38f;
        }
        __syncthreads();

        // ADD-S sweep: this wave covers q in [wv*QW, wv*QW + QW)
        const int q0 = wv * QW;
#pragma unroll 1
        for (int q = 0; q < QW; q += 4) {
#pragma unroll
            for (int j = 0; j < 4; ++j) {
                float4 t = x2s[q0 + q + j];   // wave-uniform -> LDS broadcast
#pragma unroll
                for (int i = 0; i < PPT; ++i) {
                    m[i] = fminf(m[i],
                                 fmaf(ax[i], t.x, fmaf(ay[i], t.y, fmaf(az[i], t.z, t.w))));
                }
            }
        }
        // fold n1 in (constant per p over the q-min), publish per-wave partials
#pragma unroll
        for (int i = 0; i < PPT; ++i) {
            float n1 = ax[i] * ax[i] + ay[i] * ay[i] + az[i] * az[i];
            msh[wv * PPB + lane + i * 64] = n1 + m[i];
        }
        __syncthreads();

        // cross-wave min: thread t (< PPB) owns p-slot t
        if (threadIdx.x < PPB) {
            const int sl = threadIdx.x;
            float mm = 3.0e38f;
#pragma unroll
            for (int wvi = 0; wvi < NW; ++wvi)
                mm = fminf(mm, msh[wvi * PPB + sl]);
            acc = fmaxf(0.5f * mm - MARGIN_F, 0.0f);
        }
    } else {
        // ADD: matched-point distance; threads < PPB each own one p-slot
        if (threadIdx.x < PPB) {
            const int p = part * PPB + (int)threadIdx.x;
            const float px = pt[p * 3 + 0], py = pt[p * 3 + 1], pz = pt[p * 3 + 2];
            const float ax0 = R1[0] * px + R1[1] * py + R1[2] * pz;
            const float ay0 = R1[3] * px + R1[4] * py + R1[5] * pz;
            const float az0 = R1[6] * px + R1[7] * py + R1[8] * pz;
            const float bx0 = R2[0] * px + R2[1] * py + R2[2] * pz;
            const float by0 = R2[3] * px + R2[4] * py + R2[5] * pz;
            const float bz0 = R2[6] * px + R2[7] * py + R2[8] * pz;
            const float dx = ax0 - bx0, dy = ay0 - by0, dz = az0 - bz0;
            const float d = dx * dx + dy * dy + dz * dz;
            acc = fmaxf(0.5f * d - MARGIN_F, 0.0f);
        }
    }

    // ---- block reduction: 64-lane shuffle, then 8 waves via LDS ----
#pragma unroll
    for (int off = 32; off > 0; off >>= 1)
        acc += __shfl_down(acc, off);
    __shared__ float wsum[NW];
    const int lane = threadIdx.x & 63, wid = threadIdx.x >> 6;
    if (lane == 0) wsum[wid] = acc;
    __syncthreads();
    if (threadIdx.x == 0) {
        float ssum = 0.f;
#pragma unroll
        for (int i = 0; i < NW; ++i) ssum += wsum[i];
        partials[blockIdx.x] = ssum;   // unique slot: plain store, no atomic
    }
}

// reduce NBLK partials -> single scalar (plain store, no zero-init needed)
__global__ __launch_bounds__(NBLK) void adl_reduce_kernel(
    const float* __restrict__ partials, float* __restrict__ out)
{
    float acc = partials[threadIdx.x] * (1.0f / (float)(NB * NP));
#pragma unroll
    for (int off = 32; off > 0; off >>= 1)
        acc += __shfl_down(acc, off);
    __shared__ float wsum[NBLK / 64];
    const int lane = threadIdx.x & 63, wid = threadIdx.x >> 6;
    if (lane == 0) wsum[wid] = acc;
    __syncthreads();
    if (threadIdx.x == 0) {
        float ssum = 0.f;
#pragma unroll
        for (int i = 0; i < NBLK / 64; ++i) ssum += wsum[i];
        out[0] = ssum;
    }
}

extern "C" void kernel_launch(void* const* d_in, const int* in_sizes, int n_in,
                              void* d_out, int out_size, void* d_ws, size_t ws_size,
                              hipStream_t stream) {
    const float* poses_pred   = (const float*)d_in[0];
    const float* poses_target = (const float*)d_in[1];
    const int*   poses_labels = (const int*)d_in[2];
    const float* points       = (const float*)d_in[3];
    const int*   symmetry     = (const int*)d_in[4];
    float* out      = (float*)d_out;
    float* partials = (float*)d_ws;

    adl_main_kernel<<<NBLK, TPB, 0, stream>>>(poses_pred, poses_target,
                                              poses_labels, points, symmetry,
                                              partials);
    adl_reduce_kernel<<<1, NBLK, 0, stream>>>(partials, out);
}